// Round 12
// baseline (194.692 us; speedup 1.0000x reference)
//
#include <hip/hip_runtime.h>
#include <hip/hip_fp16.h>

#define DIN 128
#define HDIM 16
#define NB 512          // dst buckets; bdiv = ceil(n/NB) must be <= BDIV_MAX
#define BDIV_MAX 256    // max nodes per bucket
#define CAPB 7168       // per-bucket record capacity (mean 6250 + ~11.6 sigma)
#define CAPP 7936       // padded per-bucket segment capacity >= CAPB + 3*bdiv
#define BIN_EPT 16      // edges per thread in bin role
#define TPB 512         // threads per block (all kernels)
#define BINSZ (TPB * BIN_EPT)   // 8192 edges per bin block

__device__ __forceinline__ float4 f4add(float4 a, float4 b) {
    return make_float4(a.x + b.x, a.y + b.y, a.z + b.z, a.w + b.w);
}

// y rows are 16 fp16 = 32 B; lane q owns 4 halves = one uint2 at row*4 + q.
__device__ __forceinline__ float4 h4_to_f4(uint2 u) {
    __half2 a = *(__half2*)&u.x, b = *(__half2*)&u.y;
    float2 fa = __half22float2(a), fb = __half22float2(b);
    return make_float4(fa.x, fa.y, fb.x, fb.y);
}
__device__ __forceinline__ uint2 f4_to_h4(float4 v) {
    __half2 a = __floats2half2_rn(v.x, v.y);
    __half2 b = __floats2half2_rn(v.z, v.w);
    uint2 u;
    u.x = *(unsigned*)&a;
    u.y = *(unsigned*)&b;
    return u;
}

__device__ __forceinline__ int load_idx(const void* ei, long long i, int is64) {
    return is64 ? (int)((const long long*)ei)[i] : ((const int*)ei)[i];
}

// ---- K1: fused edge-binning + raw layer-1 GEMM (R8 config: best measured) --
// blocks [0, nbin)        : bin edges by dst bucket into recs (relative bcur)
// blocks [nbin, nbin+nxw) : y1_raw = x @ W1 (fp16-packed); node n = zero row
// record = dloc << 18 | src   (src < 2^18, dloc < 2^10)
// Lessons: no global per-edge atomics (R7), no random scatter (R3), no LDS
// staging of recs here (R1), no grid.sync fusion (R10: cross-XCD stale reads).
__global__ __launch_bounds__(512) void k_main(const void* __restrict__ ei, long long E,
                                              int bdiv, unsigned Mdiv,
                                              int* __restrict__ bcur,
                                              unsigned int* __restrict__ recs,
                                              const float* __restrict__ x,
                                              const float* __restrict__ W1,
                                              unsigned int* __restrict__ y1,
                                              int n, int nbin) {
    __shared__ int cnt[NB];
    __shared__ int base[NB];
    __shared__ float Ws[DIN * HDIM];
    int tid = threadIdx.x;
    if ((int)blockIdx.x < nbin) {
        // ---------------- bin role ----------------
        unsigned probe = ((const unsigned*)ei)[1 + 2 * (tid & 63)];
        int is64 = (__ballot(probe != 0) == 0ull) ? 1 : 0;
        cnt[tid] = 0;                    // NB == TPB == 512
        __syncthreads();
        long long e0 = (long long)blockIdx.x * BINSZ;
        int s[BIN_EPT], dl[BIN_EPT], b[BIN_EPT];
        if (e0 + BINSZ <= E) {
            // full block: wide vector loads (coalesced 16B/lane)
            int d[BIN_EPT];
            if (is64) {
                const longlong2* ps = (const longlong2*)((const long long*)ei + e0);
                const longlong2* pd = (const longlong2*)((const long long*)ei + E + e0);
#pragma unroll
                for (int i = 0; i < BIN_EPT / 2; i++) {
                    longlong2 vs = ps[i * TPB + tid];
                    longlong2 vd = pd[i * TPB + tid];
                    s[2 * i + 0] = (int)vs.x; s[2 * i + 1] = (int)vs.y;
                    d[2 * i + 0] = (int)vd.x; d[2 * i + 1] = (int)vd.y;
                }
            } else {
                const int4* ps = (const int4*)((const int*)ei + e0);
                const int4* pd = (const int4*)((const int*)ei + E + e0);
#pragma unroll
                for (int i = 0; i < BIN_EPT / 4; i++) {
                    int4 vs = ps[i * TPB + tid];
                    int4 vd = pd[i * TPB + tid];
                    s[4 * i + 0] = vs.x; s[4 * i + 1] = vs.y;
                    s[4 * i + 2] = vs.z; s[4 * i + 3] = vs.w;
                    d[4 * i + 0] = vd.x; d[4 * i + 1] = vd.y;
                    d[4 * i + 2] = vd.z; d[4 * i + 3] = vd.w;
                }
            }
#pragma unroll
            for (int i = 0; i < BIN_EPT; i++) {
                int bb = Mdiv ? (int)__umulhi((unsigned)d[i], Mdiv) : d[i];
                b[i] = bb;
                dl[i] = d[i] - bb * bdiv;
                atomicAdd(&cnt[bb], 1);
            }
        } else {
            // tail block: scalar guarded loads
#pragma unroll
            for (int i = 0; i < BIN_EPT; i++) {
                long long e = e0 + (long long)i * TPB + tid;
                if (e < E) {
                    s[i] = load_idx(ei, e, is64);
                    int d = load_idx(ei, E + e, is64);
                    int bb = Mdiv ? (int)__umulhi((unsigned)d, Mdiv) : d;
                    b[i] = bb;
                    dl[i] = d - bb * bdiv;
                    atomicAdd(&cnt[bb], 1);
                } else {
                    b[i] = -1;
                }
            }
        }
        __syncthreads();
        base[tid] = atomicAdd(&bcur[tid], cnt[tid]);   // bcur starts at 0
        cnt[tid] = 0;
        __syncthreads();
#pragma unroll
        for (int i = 0; i < BIN_EPT; i++) {
            if (b[i] >= 0) {
                int off = atomicAdd(&cnt[b[i]], 1);
                int pos = base[b[i]] + off;
                if (pos < CAPB) {   // overflow guard (statistically never)
                    recs[(size_t)b[i] * CAPB + pos] =
                        ((unsigned)dl[i] << 18) | (unsigned)s[i];
                }
            }
        }
    } else {
        // ---------------- xw1 role ----------------
        for (int i = tid; i < DIN * HDIM; i += TPB) Ws[i] = W1[i];
        __syncthreads();
        int node = ((int)blockIdx.x - nbin) * TPB + tid;
        if (node > n) return;
        uint2* yr = (uint2*)(y1 + (size_t)node * 8);   // row = 8 uints = 4 uint2
        if (node == n) {       // dedicated zero row for padded segment entries
            uint2 z; z.x = 0u; z.y = 0u;
#pragma unroll
            for (int q = 0; q < 4; q++) yr[q] = z;
            return;
        }
        float acc[HDIM];
#pragma unroll
        for (int f = 0; f < HDIM; f++) acc[f] = 0.f;
        const float4* xr = (const float4*)(x + (size_t)node * DIN);
#pragma unroll 8
        for (int k4 = 0; k4 < DIN / 4; k4++) {
            float4 xv = xr[k4];
            int k = k4 * 4;
#pragma unroll
            for (int f = 0; f < HDIM; f++) {
                acc[f] += xv.x * Ws[(k + 0) * HDIM + f];
                acc[f] += xv.y * Ws[(k + 1) * HDIM + f];
                acc[f] += xv.z * Ws[(k + 2) * HDIM + f];
                acc[f] += xv.w * Ws[(k + 3) * HDIM + f];
            }
        }
#pragma unroll
        for (int q = 0; q < 4; q++)
            yr[q] = f4_to_h4(make_float4(acc[q * 4 + 0], acc[q * 4 + 1],
                                         acc[q * 4 + 2], acc[q * 4 + 3]));
    }
}

// ---- K2: per-bucket deg histogram from recs -> dis + scale y1 --------------
// (R7 lesson: deriving deg via global atomics in k_main is 3x worse)
__global__ __launch_bounds__(512) void k_deg(const unsigned int* __restrict__ recs,
                                             const int* __restrict__ bcur,
                                             float* __restrict__ dis,
                                             unsigned int* __restrict__ y1,
                                             int n, int bdiv) {
    __shared__ int cnt[BDIV_MAX];
    int tid = threadIdx.x, b = blockIdx.x;
    if (tid < BDIV_MAX) cnt[tid] = 0;
    __syncthreads();
    int lo = b * bdiv; if (lo > n) lo = n;
    int hi = lo + bdiv; if (hi > n) hi = n;
    int nd = hi - lo;
    int m = bcur[b]; if (m > CAPB) m = CAPB;
    const unsigned int* r = recs + (size_t)b * CAPB;
    for (int i = tid; i < m; i += 512)
        atomicAdd(&cnt[r[i] >> 18], 1);
    __syncthreads();
    int q = tid & 3, g = tid >> 2;
    uint2* yv = (uint2*)y1;
    for (int j = g; j < nd; j += 128) {
        int node = lo + j;
        float dv = rsqrtf((float)cnt[j] + 1.0f);
        if (q == 0) dis[node] = dv;
        float4 t = h4_to_f4(yv[(size_t)node * 4 + q]);
        yv[(size_t)node * 4 + q] =
            f4_to_h4(make_float4(t.x * dv, t.y * dv, t.z * dv, t.w * dv));
    }
}

// ---- K3: fused LDS counting-sort + per-node register gather + epilogue 1 ---
// R12: per bucket, sort records into per-node segments in LDS (k_prep's proven
// histogram->scan->scatter, but LDS-resident: no col write/read), then 4-lane
// groups walk each node's segment accumulating y1 rows in REGISTERS (no LDS
// atomics; R3's gather-style remainder measured ~30us faster than scatter-agg).
// Segments padded to mult-of-4 with sentinel src=n (zero row).
__global__ __launch_bounds__(512) void k_sg1(const unsigned int* __restrict__ recs,
                                             const int* __restrict__ bcur,
                                             const unsigned int* __restrict__ y1,
                                             const float* __restrict__ b1,
                                             const float* __restrict__ W2,
                                             unsigned int* __restrict__ y2,
                                             int n, int bdiv) {
    __shared__ int cnt_sh[BDIV_MAX];
    __shared__ int sc[512];
    __shared__ int stx[BDIV_MAX];
    __shared__ int dgx[BDIV_MAX];
    __shared__ unsigned int ord[CAPP];
    __shared__ float4 Ws4[HDIM][4];          // Ws4[j][q] = W2[j][4q..4q+3]
    int tid = threadIdx.x, b = blockIdx.x;
    if (tid < HDIM * 4)
        ((float4*)Ws4)[tid] = ((const float4*)W2)[tid];
    if (b == 0 && tid < 4) {   // zero row n of y2 (for k_sg2 sentinel gathers)
        uint2 z; z.x = 0u; z.y = 0u;
        ((uint2*)y2)[(size_t)n * 4 + tid] = z;
    }
    int lo = b * bdiv; if (lo > n) lo = n;
    int hi = lo + bdiv; if (hi > n) hi = n;
    int nd = hi - lo;
    if (tid < BDIV_MAX) cnt_sh[tid] = 0;
    __syncthreads();
    int m = bcur[b]; if (m > CAPB) m = CAPB;
    const unsigned int* r = recs + (size_t)b * CAPB;
    for (int i = tid; i < m; i += 512)
        atomicAdd(&cnt_sh[r[i] >> 18], 1);
    __syncthreads();
    // exclusive scan of PADDED counts (each rounded up to multiple of 4)
    int v  = (tid < nd) ? cnt_sh[tid] : 0;
    int pv = (v + 3) & ~3;
    sc[tid] = pv;
    __syncthreads();
    for (int off = 1; off < 512; off <<= 1) {
        int t = (tid >= off) ? sc[tid - off] : 0;
        __syncthreads();
        sc[tid] += t;
        __syncthreads();
    }
    int ptot = sc[511];
    if (ptot > CAPP) ptot = CAPP;            // safety (never: <= CAPB+3*bdiv)
    if (tid < nd) {
        int excl = sc[tid] - pv;
        stx[tid] = excl; dgx[tid] = v;
        cnt_sh[tid] = excl;                  // placement cursor
    }
    for (int i = tid; i < ptot; i += 512) ord[i] = (unsigned)n;  // sentinel
    __syncthreads();
    for (int i = tid; i < m; i += 512) {
        unsigned rv = r[i];
        int pos = atomicAdd(&cnt_sh[rv >> 18], 1);
        if (pos < CAPP) ord[pos] = rv & 0x3FFFFu;
    }
    __syncthreads();
    // per-node register gather + epilogue
    int q = tid & 3, g = tid >> 2;           // 128 groups of 4 lanes
    const uint2* yv = (const uint2*)y1;
    float4 bb = ((const float4*)b1)[q];
    for (int j = g; j < nd; j += 128) {
        int node = lo + j;
        int st = stx[j], dg = dgx[j];
        int pe = st + ((dg + 3) & ~3);
        float4 a0 = make_float4(0.f, 0.f, 0.f, 0.f), a1 = a0, a2 = a0, a3 = a0;
        int k = st;
        for (; k + 8 <= pe; k += 8) {
            int4 c0 = *(const int4*)&ord[k];
            int4 c1 = *(const int4*)&ord[k + 4];
            uint2 v0 = yv[(size_t)c0.x * 4 + q], v1 = yv[(size_t)c0.y * 4 + q];
            uint2 v2 = yv[(size_t)c0.z * 4 + q], v3 = yv[(size_t)c0.w * 4 + q];
            uint2 v4 = yv[(size_t)c1.x * 4 + q], v5 = yv[(size_t)c1.y * 4 + q];
            uint2 v6 = yv[(size_t)c1.z * 4 + q], v7 = yv[(size_t)c1.w * 4 + q];
            a0 = f4add(a0, h4_to_f4(v0)); a1 = f4add(a1, h4_to_f4(v1));
            a2 = f4add(a2, h4_to_f4(v2)); a3 = f4add(a3, h4_to_f4(v3));
            a0 = f4add(a0, h4_to_f4(v4)); a1 = f4add(a1, h4_to_f4(v5));
            a2 = f4add(a2, h4_to_f4(v6)); a3 = f4add(a3, h4_to_f4(v7));
        }
        for (; k < pe; k += 4) {
            int4 c0 = *(const int4*)&ord[k];
            uint2 v0 = yv[(size_t)c0.x * 4 + q], v1 = yv[(size_t)c0.y * 4 + q];
            uint2 v2 = yv[(size_t)c0.z * 4 + q], v3 = yv[(size_t)c0.w * 4 + q];
            a0 = f4add(a0, h4_to_f4(v0)); a1 = f4add(a1, h4_to_f4(v1));
            a2 = f4add(a2, h4_to_f4(v2)); a3 = f4add(a3, h4_to_f4(v3));
        }
        float4 acc = f4add(f4add(a0, a1), f4add(a2, a3));
        acc = f4add(acc, h4_to_f4(yv[(size_t)node * 4 + q]));  // self-loop term
        float dv = rsqrtf((float)dg + 1.0f);
        float4 h;
        h.x = fmaxf(dv * acc.x + bb.x, 0.f);
        h.y = fmaxf(dv * acc.y + bb.y, 0.f);
        h.z = fmaxf(dv * acc.z + bb.z, 0.f);
        h.w = fmaxf(dv * acc.w + bb.w, 0.f);
        float4 o = make_float4(0.f, 0.f, 0.f, 0.f);
#pragma unroll
        for (int kk = 0; kk < 4; kk++) {
            float4 hk;
            hk.x = __shfl(h.x, kk, 4); hk.y = __shfl(h.y, kk, 4);
            hk.z = __shfl(h.z, kk, 4); hk.w = __shfl(h.w, kk, 4);
            float hv[4] = {hk.x, hk.y, hk.z, hk.w};
#pragma unroll
            for (int c = 0; c < 4; c++) {
                float4 w = Ws4[kk * 4 + c][q];
                o.x += hv[c] * w.x; o.y += hv[c] * w.y;
                o.z += hv[c] * w.z; o.w += hv[c] * w.w;
            }
        }
        ((uint2*)y2)[(size_t)node * 4 + q] =
            f4_to_h4(make_float4(o.x * dv, o.y * dv, o.z * dv, o.w * dv));
    }
}

// ---- K4: fused LDS counting-sort + register gather + final epilogue --------
// out = relu(dv*(gather+self)+b2) . Wlin + blin
__global__ __launch_bounds__(512) void k_sg2(const unsigned int* __restrict__ recs,
                                             const int* __restrict__ bcur,
                                             const unsigned int* __restrict__ y2,
                                             const float* __restrict__ b2,
                                             const float* __restrict__ Wlin,
                                             const float* __restrict__ blin,
                                             float* __restrict__ out,
                                             int n, int bdiv) {
    __shared__ int cnt_sh[BDIV_MAX];
    __shared__ int sc[512];
    __shared__ int stx[BDIV_MAX];
    __shared__ int dgx[BDIV_MAX];
    __shared__ unsigned int ord[CAPP];
    int tid = threadIdx.x, b = blockIdx.x;
    int lo = b * bdiv; if (lo > n) lo = n;
    int hi = lo + bdiv; if (hi > n) hi = n;
    int nd = hi - lo;
    if (tid < BDIV_MAX) cnt_sh[tid] = 0;
    __syncthreads();
    int m = bcur[b]; if (m > CAPB) m = CAPB;
    const unsigned int* r = recs + (size_t)b * CAPB;
    for (int i = tid; i < m; i += 512)
        atomicAdd(&cnt_sh[r[i] >> 18], 1);
    __syncthreads();
    int v  = (tid < nd) ? cnt_sh[tid] : 0;
    int pv = (v + 3) & ~3;
    sc[tid] = pv;
    __syncthreads();
    for (int off = 1; off < 512; off <<= 1) {
        int t = (tid >= off) ? sc[tid - off] : 0;
        __syncthreads();
        sc[tid] += t;
        __syncthreads();
    }
    int ptot = sc[511];
    if (ptot > CAPP) ptot = CAPP;
    if (tid < nd) {
        int excl = sc[tid] - pv;
        stx[tid] = excl; dgx[tid] = v;
        cnt_sh[tid] = excl;
    }
    for (int i = tid; i < ptot; i += 512) ord[i] = (unsigned)n;
    __syncthreads();
    for (int i = tid; i < m; i += 512) {
        unsigned rv = r[i];
        int pos = atomicAdd(&cnt_sh[rv >> 18], 1);
        if (pos < CAPP) ord[pos] = rv & 0x3FFFFu;
    }
    __syncthreads();
    int q = tid & 3, g = tid >> 2;
    const uint2* yv = (const uint2*)y2;
    float4 bb = ((const float4*)b2)[q];
    float4 wl = ((const float4*)Wlin)[q];
    for (int j = g; j < nd; j += 128) {
        int node = lo + j;
        int st = stx[j], dg = dgx[j];
        int pe = st + ((dg + 3) & ~3);
        float4 a0 = make_float4(0.f, 0.f, 0.f, 0.f), a1 = a0, a2 = a0, a3 = a0;
        int k = st;
        for (; k + 8 <= pe; k += 8) {
            int4 c0 = *(const int4*)&ord[k];
            int4 c1 = *(const int4*)&ord[k + 4];
            uint2 v0 = yv[(size_t)c0.x * 4 + q], v1 = yv[(size_t)c0.y * 4 + q];
            uint2 v2 = yv[(size_t)c0.z * 4 + q], v3 = yv[(size_t)c0.w * 4 + q];
            uint2 v4 = yv[(size_t)c1.x * 4 + q], v5 = yv[(size_t)c1.y * 4 + q];
            uint2 v6 = yv[(size_t)c1.z * 4 + q], v7 = yv[(size_t)c1.w * 4 + q];
            a0 = f4add(a0, h4_to_f4(v0)); a1 = f4add(a1, h4_to_f4(v1));
            a2 = f4add(a2, h4_to_f4(v2)); a3 = f4add(a3, h4_to_f4(v3));
            a0 = f4add(a0, h4_to_f4(v4)); a1 = f4add(a1, h4_to_f4(v5));
            a2 = f4add(a2, h4_to_f4(v6)); a3 = f4add(a3, h4_to_f4(v7));
        }
        for (; k < pe; k += 4) {
            int4 c0 = *(const int4*)&ord[k];
            uint2 v0 = yv[(size_t)c0.x * 4 + q], v1 = yv[(size_t)c0.y * 4 + q];
            uint2 v2 = yv[(size_t)c0.z * 4 + q], v3 = yv[(size_t)c0.w * 4 + q];
            a0 = f4add(a0, h4_to_f4(v0)); a1 = f4add(a1, h4_to_f4(v1));
            a2 = f4add(a2, h4_to_f4(v2)); a3 = f4add(a3, h4_to_f4(v3));
        }
        float4 acc = f4add(f4add(a0, a1), f4add(a2, a3));
        acc = f4add(acc, h4_to_f4(yv[(size_t)node * 4 + q]));  // self-loop term
        float dv = rsqrtf((float)dg + 1.0f);
        float vv = 0.f;
        vv += fmaxf(dv * acc.x + bb.x, 0.f) * wl.x;
        vv += fmaxf(dv * acc.y + bb.y, 0.f) * wl.y;
        vv += fmaxf(dv * acc.z + bb.z, 0.f) * wl.z;
        vv += fmaxf(dv * acc.w + bb.w, 0.f) * wl.w;
        vv += __shfl_xor(vv, 1, 4);
        vv += __shfl_xor(vv, 2, 4);
        if (q == 0) out[node] = vv + blin[0];
    }
}

extern "C" void kernel_launch(void* const* d_in, const int* in_sizes, int n_in,
                              void* d_out, int out_size, void* d_ws, size_t ws_size,
                              hipStream_t stream) {
    const float* x    = (const float*)d_in[0];
    const void*  ei   = d_in[1];
    const float* W1   = (const float*)d_in[2];
    const float* b1   = (const float*)d_in[3];
    const float* W2   = (const float*)d_in[4];
    const float* b2   = (const float*)d_in[5];
    const float* Wlin = (const float*)d_in[6];
    const float* blin = (const float*)d_in[7];
    float* out = (float*)d_out;

    const int n = in_sizes[0] / DIN;          // 100000 (needs n <= NB*BDIV_MAX, n < 2^18)
    const long long E = in_sizes[1] / 2;      // 3200000
    const int bdiv = (n + NB - 1) / NB;       // 196 (<= BDIV_MAX)
    // magic multiplier for d / bdiv (exact for d < 2^17 when bdiv >= 2)
    const unsigned Mdiv = (bdiv > 1)
        ? (unsigned)(((1ull << 32) + (unsigned)bdiv - 1) / (unsigned)bdiv) : 0u;

    // workspace layout (256B-aligned). y rows are 16 fp16 = 8 uints (+1 zero row).
    char* ws = (char*)d_ws;
    size_t off = 0;
    auto alloc = [&](size_t bytes) { char* p = ws + off; off += (bytes + 255) & ~(size_t)255; return p; };
    int*   bcur = (int*)alloc(NB * 4);
    float* dis  = (float*)alloc((size_t)n * 4);
    unsigned int* y1 = (unsigned int*)alloc((size_t)(n + 1) * 8 * 4);
    unsigned int* y2 = (unsigned int*)alloc((size_t)(n + 1) * 8 * 4);
    unsigned int* recs = (unsigned int*)alloc((size_t)NB * CAPB * 4);   // 14.7 MB

    const int nb_xw  = (n + 1 + TPB - 1) / TPB;        // 196
    const int nb_bin = (int)((E + BINSZ - 1) / BINSZ); // 391

    hipMemsetAsync(bcur, 0, NB * sizeof(int), stream);
    k_main<<<nb_bin + nb_xw, TPB, 0, stream>>>(ei, E, bdiv, Mdiv, bcur, recs, x, W1, y1, n, nb_bin);
    k_deg<<<NB, 512, 0, stream>>>(recs, bcur, dis, y1, n, bdiv);
    k_sg1<<<NB, 512, 0, stream>>>(recs, bcur, y1, b1, W2, y2, n, bdiv);
    k_sg2<<<NB, 512, 0, stream>>>(recs, bcur, y2, b2, Wlin, blin, out, n, bdiv);
}